// Round 1
// baseline (2153.989 us; speedup 1.0000x reference)
//
#include <hip/hip_runtime.h>
#include <hip/hip_bf16.h>

#define NUM_ENT   50000
#define NUM_RELC  500
#define KTOP      50
#define EMB       400
#define FEAT      1000
#define N_NODES   50500
#define N_EDGES   400000
#define BATCH     4096
#define RELM1     499     // NUM_REL - 1

// ---------------- logits: rel_feat @ Wp.T + bp  (499 dots of length 1000) ----
__global__ void logits_kernel(const float* __restrict__ nf, const float* __restrict__ Wp,
                              const float* __restrict__ bp, float* __restrict__ logits) {
    __shared__ float red[256];
    int i = blockIdx.x, t = threadIdx.x;
    float s = 0.f;
    for (int k = t; k < FEAT; k += 256) s += nf[(size_t)i * FEAT + k] * Wp[k];
    red[t] = s; __syncthreads();
    for (int st = 128; st > 0; st >>= 1) { if (t < st) red[t] += red[t + st]; __syncthreads(); }
    if (t == 0) logits[i] = red[0] + bp[0];
}

// ---------------- softmax over 499 + top-50 (sorted ascending) ---------------
__global__ void topk_kernel(const float* __restrict__ logits, int* __restrict__ idxbuf,
                            float* __restrict__ probsel) {
    __shared__ float l[RELM1];
    __shared__ float p[RELM1];
    __shared__ int   flag[RELM1];
    __shared__ float red[512];
    int t = threadIdx.x;  // 512 threads
    float v = (t < RELM1) ? logits[t] : -1e30f;
    if (t < RELM1) l[t] = v;
    red[t] = v; __syncthreads();
    for (int s = 256; s > 0; s >>= 1) { if (t < s) red[t] = fmaxf(red[t], red[t + s]); __syncthreads(); }
    float m = red[0]; __syncthreads();
    float e = (t < RELM1) ? expf(v - m) : 0.f;
    red[t] = e; __syncthreads();
    for (int s = 256; s > 0; s >>= 1) { if (t < s) red[t] += red[t + s]; __syncthreads(); }
    float denom = red[0];
    if (t < RELM1) p[t] = e / denom;
    __syncthreads();
    if (t < RELM1) {
        float lv = l[t]; int cnt = 0;
        for (int j = 0; j < RELM1; j++) {
            float lj = l[j];
            cnt += (lj > lv) || (lj == lv && j < t);
        }
        flag[t] = (cnt < KTOP);
    }
    __syncthreads();
    if (t == 0) {
        int n = 0;
        for (int i = 0; i < RELM1; i++)
            if (flag[i]) { idxbuf[n] = i; probsel[n] = p[i]; n++; }
    }
}

// ---------------- ra = concat(anchor, num_feature[idx]*prob[idx]) ------------
__global__ void build_ra(const float* __restrict__ anchor, const float* __restrict__ nf,
                         const int* __restrict__ idxbuf, const float* __restrict__ probsel,
                         float* __restrict__ ra) {
    int r = blockIdx.x, t = threadIdx.x;
    if (r < KTOP) {
        for (int k = t; k < FEAT; k += 256) ra[r * FEAT + k] = anchor[r * FEAT + k];
    } else {
        int j = r - KTOP; int src = idxbuf[j]; float pp = probsel[j];
        for (int k = t; k < FEAT; k += 256) ra[r * FEAT + k] = nf[(size_t)src * FEAT + k] * pp;
    }
}

// ---------------- raw = ra @ Wa   (100x1000 @ 1000x1000) ---------------------
__global__ void gemm_small(const float* __restrict__ ra, const float* __restrict__ Wa,
                           float* __restrict__ raw) {
    __shared__ float row[FEAT];
    int r = blockIdx.x, t = threadIdx.x;
    for (int k = t; k < FEAT; k += 256) row[k] = ra[r * FEAT + k];
    __syncthreads();
    float a0 = 0.f, a1 = 0.f, a2 = 0.f, a3 = 0.f;
    for (int k = 0; k < FEAT; k++) {
        float rv = row[k];
        const float* wrow = Wa + (size_t)k * FEAT;
        a0 += rv * wrow[t];
        a1 += rv * wrow[t + 256];
        a2 += rv * wrow[t + 512];
        if (t < 232) a3 += rv * wrow[t + 768];
    }
    raw[r * FEAT + t]       = a0;
    raw[r * FEAT + t + 256] = a1;
    raw[r * FEAT + t + 512] = a2;
    if (t < 232) raw[r * FEAT + t + 768] = a3;
}

// ---------------- degree + dinv ----------------------------------------------
__global__ void deg_kernel(const int* __restrict__ ei, int nedges, float* __restrict__ deg) {
    int e = blockIdx.x * 256 + threadIdx.x;
    if (e < nedges) { int dst = ei[nedges + e]; atomicAdd(&deg[dst], 1.0f); }
}
__global__ void dinv_kernel(float* __restrict__ deg, int n) {
    int i = blockIdx.x * 256 + threadIdx.x;
    if (i < n) deg[i] = 1.0f / sqrtf(deg[i] + 1.0f);
}

// ---------------- small GCN scatter + finalize -------------------------------
__global__ void scatter_small(const int* __restrict__ ei, const float* __restrict__ raw,
                              const float* __restrict__ dinv_s, float* __restrict__ acc) {
    int wave = threadIdx.x >> 6, lane = threadIdx.x & 63;
    int e = blockIdx.x * 4 + wave;
    if (e >= 2000) return;
    int src = ei[e], dst = ei[2000 + e];
    float c = dinv_s[src] * dinv_s[dst];
    const float* rs = raw + (size_t)src * FEAT;
    float* ad = acc + (size_t)dst * FEAT;
    for (int k = lane; k < FEAT; k += 64) atomicAdd(&ad[k], rs[k] * c);
}
__global__ void finalize_small(const float* __restrict__ raw, const float* __restrict__ dinv_s,
                               const float* __restrict__ ba, float* __restrict__ x1s) {
    int r = blockIdx.x, t = threadIdx.x;
    float d2 = dinv_s[r] * dinv_s[r];
    for (int k = t; k < FEAT; k += 256) {
        float v = x1s[r * FEAT + k] + raw[r * FEAT + k] * d2 + ba[k];
        x1s[r * FEAT + k] = fmaxf(v, 0.f);
    }
}

// ---------------- big GEMM: xw = num_feature @ W1 (50500x1000 @ 1000x400) ----
#define BM 64
#define BN 64
#define BKg 16
__global__ __launch_bounds__(256) void gemm_big(const float* __restrict__ A,
                                                const float* __restrict__ B,
                                                float* __restrict__ C) {
    __shared__ float As[BKg][BM + 4];
    __shared__ float Bs[BKg][BN];
    int n0 = blockIdx.x * BN, m0 = blockIdx.y * BM;
    int t = threadIdx.x;
    int ty = t >> 4, tx = t & 15;
    float acc[4][4] = {};
    for (int k0 = 0; k0 < FEAT; k0 += BKg) {
        for (int e = t; e < BM * BKg; e += 256) {
            int m = e >> 4, k = e & 15;
            int gm = m0 + m, gk = k0 + k;
            As[k][m] = (gm < N_NODES && gk < FEAT) ? A[(size_t)gm * FEAT + gk] : 0.f;
        }
        for (int e = t; e < BKg * BN; e += 256) {
            int k = e >> 6, n = e & 63;
            int gk = k0 + k, gn = n0 + n;
            Bs[k][n] = (gk < FEAT && gn < EMB) ? B[(size_t)gk * EMB + gn] : 0.f;
        }
        __syncthreads();
        for (int kk = 0; kk < BKg; kk++) {
            float4 a4 = *reinterpret_cast<const float4*>(&As[kk][ty * 4]);
            float4 b4 = *reinterpret_cast<const float4*>(&Bs[kk][tx * 4]);
            float av[4] = {a4.x, a4.y, a4.z, a4.w};
            float bv[4] = {b4.x, b4.y, b4.z, b4.w};
            for (int i = 0; i < 4; i++)
                for (int j = 0; j < 4; j++)
                    acc[i][j] += av[i] * bv[j];
        }
        __syncthreads();
    }
    for (int i = 0; i < 4; i++) {
        int gm = m0 + ty * 4 + i; if (gm >= N_NODES) continue;
        for (int j = 0; j < 4; j++) {
            int gn = n0 + tx * 4 + j; if (gn >= EMB) continue;
            C[(size_t)gm * EMB + gn] = acc[i][j];
        }
    }
}

// ---------------- big GCN scatter + finalize ---------------------------------
__global__ void scatter_big(const int* __restrict__ ei, const float* __restrict__ xw,
                            const float* __restrict__ dinv, float* __restrict__ x) {
    int wave = threadIdx.x >> 6, lane = threadIdx.x & 63;
    int base = blockIdx.x * 16 + wave * 4;
    for (int q = 0; q < 4; q++) {
        int e = base + q;
        if (e >= N_EDGES) return;
        int src = ei[e], dst = ei[N_EDGES + e];
        float c = dinv[src] * dinv[dst];
        const float* xr = xw + (size_t)src * EMB;
        float* xd = x + (size_t)dst * EMB;
        for (int k = lane; k < EMB; k += 64) atomicAdd(&xd[k], xr[k] * c);
    }
}
__global__ void finalize_big(const float* __restrict__ xw, const float* __restrict__ dinv,
                             const float* __restrict__ b1, float* __restrict__ x) {
    int wave = threadIdx.x >> 6, lane = threadIdx.x & 63;
    int r = blockIdx.x * 4 + wave;
    if (r >= N_NODES) return;
    float d2 = dinv[r] * dinv[r];
    for (int k = lane; k < EMB; k += 64) {
        float v = x[(size_t)r * EMB + k] + xw[(size_t)r * EMB + k] * d2 + b1[k];
        x[(size_t)r * EMB + k] = fmaxf(v, 0.f);
    }
}

// ---------------- temp = num_feature copy, then row replace ------------------
__global__ void copy_temp(const float* __restrict__ nf, float* __restrict__ temp) {
    size_t i = (size_t)blockIdx.x * blockDim.x + threadIdx.x;
    size_t stride = (size_t)gridDim.x * blockDim.x;
    const float4* src = (const float4*)nf;
    float4* dst = (float4*)temp;
    size_t n4 = (size_t)N_NODES * FEAT / 4;
    for (; i < n4; i += stride) dst[i] = src[i];
}
__global__ void set_rows(const float* __restrict__ x1s, const int* __restrict__ idxbuf,
                         float* __restrict__ temp) {
    int j = blockIdx.x, t = threadIdx.x;
    int r = idxbuf[j];
    for (int k = t; k < FEAT; k += 256)
        temp[(size_t)r * FEAT + k] = x1s[(size_t)(KTOP + j) * FEAT + k];
}

// ---------------- ConvE-ish scoring ------------------------------------------
__global__ void score_kernel(const float* __restrict__ ent, const float* __restrict__ rel,
                             const int* __restrict__ r_idx, const int* __restrict__ e1_idx,
                             const int* __restrict__ e2_idx, const float* __restrict__ conv_w,
                             const float* __restrict__ conv_b, const float* __restrict__ fc_w,
                             const float* __restrict__ fc_b, float* __restrict__ out) {
    __shared__ float cw[24];
    __shared__ float cb[8];
    int t = threadIdx.x;
    if (t < 24) cw[t] = conv_w[t];
    if (t < 8)  cb[t] = conv_b[t];
    __syncthreads();
    int wave = t >> 6, lane = t & 63;
    int b = blockIdx.x * 4 + wave;
    if (b >= BATCH) return;
    const float* r  = rel + (size_t)r_idx[b] * EMB;
    const float* e1 = ent + (size_t)e1_idx[b] * EMB;
    const float* e2 = ent + (size_t)e2_idx[b] * EMB;
    float partial = 0.f;
    for (int p = lane; p < EMB; p += 64) {
        float c0 = r[p], c1 = e1[p], c2 = e2[p];
        for (int g = 0; g < 4; g++) {
            float h0 = c0 * cw[(2 * g) * 3 + 0] + c1 * cw[(2 * g) * 3 + 1] + c2 * cw[(2 * g) * 3 + 2] + cb[2 * g];
            float h1 = c0 * cw[(2 * g + 1) * 3 + 0] + c1 * cw[(2 * g + 1) * 3 + 1] + c2 * cw[(2 * g + 1) * 3 + 2] + cb[2 * g + 1];
            partial += fmaxf(h0, h1) * fc_w[g * EMB + p];
        }
    }
    for (int off = 32; off > 0; off >>= 1) partial += __shfl_down(partial, off, 64);
    if (lane == 0) out[b] = partial + fc_b[0];
}

extern "C" void kernel_launch(void* const* d_in, const int* in_sizes, int n_in,
                              void* d_out, int out_size, void* d_ws, size_t ws_size,
                              hipStream_t stream) {
    const float* num_feature = (const float*)d_in[0];
    const float* anchor      = (const float*)d_in[1];
    const float* Wp          = (const float*)d_in[2];
    const float* bp          = (const float*)d_in[3];
    const float* Wa          = (const float*)d_in[4];
    const float* ba          = (const float*)d_in[5];
    const float* W1          = (const float*)d_in[6];
    const float* b1          = (const float*)d_in[7];
    const float* ent_emb     = (const float*)d_in[8];
    const float* rel_emb     = (const float*)d_in[9];
    const float* conv_w      = (const float*)d_in[10];
    const float* conv_b      = (const float*)d_in[11];
    const float* fc_w        = (const float*)d_in[12];
    const float* fc_b        = (const float*)d_in[13];
    const int*   edge_index  = (const int*)d_in[14];
    const int*   ra_edge     = (const int*)d_in[15];
    const int*   r_idx       = (const int*)d_in[16];
    const int*   e1_idx      = (const int*)d_in[17];
    const int*   e2_idx      = (const int*)d_in[18];

    float* out_score = (float*)d_out;                       // 4096
    float* out_x     = out_score + BATCH;                   // 50500*400
    float* out_temp  = out_x + (size_t)N_NODES * EMB;       // 50500*1000
    float* xw        = out_temp;  // scratch: overwritten later by copy_temp

    float* ws_f    = (float*)d_ws;
    float* logits  = ws_f;                 // 512
    int*   idxbuf  = (int*)(ws_f + 512);   // 64
    float* probsel = ws_f + 576;           // 64
    float* dinv_s  = ws_f + 640;           // 128
    float* ra      = ws_f + 768;           // 100000
    float* raw     = ws_f + 100768;        // 100000
    float* x1s     = ws_f + 200768;        // 100000
    float* dinv    = ws_f + 300768;        // 50500  -> total 351268 floats

    hipMemsetAsync(d_ws, 0, 351268 * sizeof(float), stream);
    hipMemsetAsync(out_x, 0, (size_t)N_NODES * EMB * sizeof(float), stream);

    logits_kernel<<<RELM1, 256, 0, stream>>>(num_feature, Wp, bp, logits);
    topk_kernel<<<1, 512, 0, stream>>>(logits, idxbuf, probsel);
    build_ra<<<2 * KTOP, 256, 0, stream>>>(anchor, num_feature, idxbuf, probsel, ra);
    gemm_small<<<2 * KTOP, 256, 0, stream>>>(ra, Wa, raw);
    deg_kernel<<<8, 256, 0, stream>>>(ra_edge, 2000, dinv_s);
    dinv_kernel<<<1, 256, 0, stream>>>(dinv_s, 2 * KTOP);
    scatter_small<<<500, 256, 0, stream>>>(ra_edge, raw, dinv_s, x1s);
    finalize_small<<<2 * KTOP, 256, 0, stream>>>(raw, dinv_s, ba, x1s);

    deg_kernel<<<(N_EDGES + 255) / 256, 256, 0, stream>>>(edge_index, N_EDGES, dinv);
    dinv_kernel<<<(N_NODES + 255) / 256, 256, 0, stream>>>(dinv, N_NODES);
    gemm_big<<<dim3((EMB + BN - 1) / BN, (N_NODES + BM - 1) / BM), 256, 0, stream>>>(num_feature, W1, xw);
    scatter_big<<<N_EDGES / 16, 256, 0, stream>>>(edge_index, xw, dinv, out_x);
    finalize_big<<<(N_NODES + 3) / 4, 256, 0, stream>>>(xw, dinv, b1, out_x);

    copy_temp<<<4096, 256, 0, stream>>>(num_feature, out_temp);
    set_rows<<<KTOP, 256, 0, stream>>>(x1s, idxbuf, out_temp);

    score_kernel<<<BATCH / 4, 256, 0, stream>>>(ent_emb, rel_emb, r_idx, e1_idx, e2_idx,
                                                conv_w, conv_b, fc_w, fc_b, out_score);
}

// Round 2
// 1361.607 us; speedup vs baseline: 1.5819x; 1.5819x over previous
//
#include <hip/hip_runtime.h>
#include <hip/hip_bf16.h>

#define NUM_ENT   50000
#define NUM_RELC  500
#define KTOP      50
#define EMB       400
#define FEAT      1000
#define N_NODES   50500
#define N_EDGES   400000
#define BATCH     4096
#define RELM1     499     // NUM_REL - 1

// padded GEMM dims
#define KP   1024         // FEAT padded to mult of 64
#define MP   50560        // N_NODES padded to 395*128
#define NP   512          // EMB padded to mult of 128

typedef __attribute__((ext_vector_type(8))) short short8;
typedef __attribute__((ext_vector_type(4))) float f32x4;

// ---------------- logits: rel_feat @ Wp.T + bp  (499 dots of length 1000) ----
__global__ void logits_kernel(const float* __restrict__ nf, const float* __restrict__ Wp,
                              const float* __restrict__ bp, float* __restrict__ logits) {
    __shared__ float red[256];
    int i = blockIdx.x, t = threadIdx.x;
    float s = 0.f;
    for (int k = t; k < FEAT; k += 256) s += nf[(size_t)i * FEAT + k] * Wp[k];
    red[t] = s; __syncthreads();
    for (int st = 128; st > 0; st >>= 1) { if (t < st) red[t] += red[t + st]; __syncthreads(); }
    if (t == 0) logits[i] = red[0] + bp[0];
}

// ---------------- softmax over 499 + top-50 (sorted ascending) ---------------
__global__ void topk_kernel(const float* __restrict__ logits, int* __restrict__ idxbuf,
                            float* __restrict__ probsel) {
    __shared__ float l[RELM1];
    __shared__ float p[RELM1];
    __shared__ int   flag[RELM1];
    __shared__ float red[512];
    int t = threadIdx.x;  // 512 threads
    float v = (t < RELM1) ? logits[t] : -1e30f;
    if (t < RELM1) l[t] = v;
    red[t] = v; __syncthreads();
    for (int s = 256; s > 0; s >>= 1) { if (t < s) red[t] = fmaxf(red[t], red[t + s]); __syncthreads(); }
    float m = red[0]; __syncthreads();
    float e = (t < RELM1) ? expf(v - m) : 0.f;
    red[t] = e; __syncthreads();
    for (int s = 256; s > 0; s >>= 1) { if (t < s) red[t] += red[t + s]; __syncthreads(); }
    float denom = red[0];
    if (t < RELM1) p[t] = e / denom;
    __syncthreads();
    if (t < RELM1) {
        float lv = l[t]; int cnt = 0;
        for (int j = 0; j < RELM1; j++) {
            float lj = l[j];
            cnt += (lj > lv) || (lj == lv && j < t);
        }
        flag[t] = (cnt < KTOP);
    }
    __syncthreads();
    if (t == 0) {
        int n = 0;
        for (int i = 0; i < RELM1; i++)
            if (flag[i]) { idxbuf[n] = i; probsel[n] = p[i]; n++; }
    }
}

// ---------------- ra = concat(anchor, num_feature[idx]*prob[idx]) ------------
__global__ void build_ra(const float* __restrict__ anchor, const float* __restrict__ nf,
                         const int* __restrict__ idxbuf, const float* __restrict__ probsel,
                         float* __restrict__ ra) {
    int r = blockIdx.x, t = threadIdx.x;
    if (r < KTOP) {
        for (int k = t; k < FEAT; k += 256) ra[r * FEAT + k] = anchor[r * FEAT + k];
    } else {
        int j = r - KTOP; int src = idxbuf[j]; float pp = probsel[j];
        for (int k = t; k < FEAT; k += 256) ra[r * FEAT + k] = nf[(size_t)src * FEAT + k] * pp;
    }
}

// ---------------- raw = ra @ Wa   (100x1000 @ 1000x1000) ---------------------
__global__ void gemm_small(const float* __restrict__ ra, const float* __restrict__ Wa,
                           float* __restrict__ raw) {
    __shared__ float row[FEAT];
    int r = blockIdx.x, t = threadIdx.x;
    for (int k = t; k < FEAT; k += 256) row[k] = ra[r * FEAT + k];
    __syncthreads();
    float a0 = 0.f, a1 = 0.f, a2 = 0.f, a3 = 0.f;
    for (int k = 0; k < FEAT; k++) {
        float rv = row[k];
        const float* wrow = Wa + (size_t)k * FEAT;
        a0 += rv * wrow[t];
        a1 += rv * wrow[t + 256];
        a2 += rv * wrow[t + 512];
        if (t < 232) a3 += rv * wrow[t + 768];
    }
    raw[r * FEAT + t]       = a0;
    raw[r * FEAT + t + 256] = a1;
    raw[r * FEAT + t + 512] = a2;
    if (t < 232) raw[r * FEAT + t + 768] = a3;
}

// ---------------- degree + dinv ----------------------------------------------
__global__ void deg_kernel(const int* __restrict__ ei, int nedges, float* __restrict__ deg) {
    int e = blockIdx.x * 256 + threadIdx.x;
    if (e < nedges) { int dst = ei[nedges + e]; atomicAdd(&deg[dst], 1.0f); }
}
__global__ void dinv_kernel(float* __restrict__ deg, int n) {
    int i = blockIdx.x * 256 + threadIdx.x;
    if (i < n) deg[i] = 1.0f / sqrtf(deg[i] + 1.0f);
}

// ---------------- small GCN scatter + finalize -------------------------------
__global__ void scatter_small(const int* __restrict__ ei, const float* __restrict__ raw,
                              const float* __restrict__ dinv_s, float* __restrict__ acc) {
    int wave = threadIdx.x >> 6, lane = threadIdx.x & 63;
    int e = blockIdx.x * 4 + wave;
    if (e >= 2000) return;
    int src = ei[e], dst = ei[2000 + e];
    float c = dinv_s[src] * dinv_s[dst];
    const float* rs = raw + (size_t)src * FEAT;
    float* ad = acc + (size_t)dst * FEAT;
    for (int k = lane; k < FEAT; k += 64) atomicAdd(&ad[k], rs[k] * c);
}
__global__ void finalize_small(const float* __restrict__ raw, const float* __restrict__ dinv_s,
                               const float* __restrict__ ba, float* __restrict__ x1s) {
    int r = blockIdx.x, t = threadIdx.x;
    float d2 = dinv_s[r] * dinv_s[r];
    for (int k = t; k < FEAT; k += 256) {
        float v = x1s[r * FEAT + k] + raw[r * FEAT + k] * d2 + ba[k];
        x1s[r * FEAT + k] = fmaxf(v, 0.f);
    }
}

// ---------------- bf16 conversion: A = num_feature -> [MP][KP] bf16 ----------
__global__ void convertA(const float* __restrict__ nf, ushort* __restrict__ Abf) {
    size_t idx = (size_t)blockIdx.x * 256 + threadIdx.x;
    size_t stride = (size_t)gridDim.x * 256;
    size_t total = (size_t)MP * KP / 8;     // 8 bf16 per thread-chunk
    for (; idx < total; idx += stride) {
        int row = (int)(idx >> 7);          // KP/8 = 128 chunks per row
        int kb  = (int)(idx & 127);
        ushort v[8];
        if (row < N_NODES && kb < 125) {    // 125*8 = 1000 = FEAT
            const float* src = nf + (size_t)row * FEAT + kb * 8;
            #pragma unroll
            for (int j = 0; j < 8; j++) {
                __hip_bfloat16 h = __float2bfloat16(src[j]);
                v[j] = *(ushort*)&h;
            }
        } else {
            #pragma unroll
            for (int j = 0; j < 8; j++) v[j] = 0;
        }
        *(uint4*)&Abf[idx * 8] = *(uint4*)v;
    }
}

// ---------------- bf16 conversion: Bt[n][k] = W1[k][n] -> [NP][KP] bf16 ------
__global__ void convertBt(const float* __restrict__ W1, ushort* __restrict__ Btbf) {
    int idx = blockIdx.x * 256 + threadIdx.x;  // NP*KP = 524288 total
    if (idx >= NP * KP) return;
    int n = idx >> 10;       // /KP
    int k = idx & 1023;
    ushort out = 0;
    if (n < EMB && k < FEAT) {
        __hip_bfloat16 h = __float2bfloat16(W1[(size_t)k * EMB + n]);
        out = *(ushort*)&h;
    }
    Btbf[idx] = out;
}

// ---------------- MFMA GEMM: xw = A(bf16) @ Bt(bf16)^T  [MPxKP]x[NPxKP]^T ----
// 128x128 tile, BK=64, 4 waves (2x2), global_load_lds + XOR-swizzled LDS.
__global__ __launch_bounds__(256) void gemm_mfma(const ushort* __restrict__ A,
                                                 const ushort* __restrict__ Bt,
                                                 float* __restrict__ C) {
    __shared__ ushort As[128 * 64];   // 16 KB, swizzled rows of 64 ushorts (128B)
    __shared__ ushort Bs[128 * 64];   // 16 KB
    int t = threadIdx.x;
    int m0 = blockIdx.x * 128;
    int n0 = blockIdx.y * 128;

    // staging geometry: per round r (4 rounds per tile per matrix),
    // thread t loads 16B: row = r*32 + (t>>3), in-row 16B-slot kb = t&7.
    // Both-sides swizzle: LDS stays linear; global source column is
    // pre-swizzled kbx = kb ^ (row&7); read side applies the same XOR.
    int srow = t >> 3;                     // 0..31
    int kbx  = (t & 7) ^ (srow & 7);       // involution within 8-row stripe

    int lane = t & 63;
    int wv   = t >> 6;
    int wr   = wv >> 1, wc = wv & 1;       // wave -> 64x64 quadrant
    int l15  = lane & 15, lhi = lane >> 4;

    f32x4 acc[4][4];
    #pragma unroll
    for (int m = 0; m < 4; m++)
        #pragma unroll
        for (int n = 0; n < 4; n++) acc[m][n] = (f32x4){0.f, 0.f, 0.f, 0.f};

    for (int kt = 0; kt < KP / 64; kt++) {
        int k0 = kt * 64;
        // ---- stage A and B tiles (4 rounds each, 16B per lane) ----
        #pragma unroll
        for (int r = 0; r < 4; r++) {
            int row = r * 32 + srow;
            const ushort* ga = A  + (size_t)(m0 + row) * KP + k0 + kbx * 8;
            const ushort* gb = Bt + (size_t)(n0 + row) * KP + k0 + kbx * 8;
            ushort* la = &As[(size_t)row * 64 + (t & 7) * 8];
            ushort* lb = &Bs[(size_t)row * 64 + (t & 7) * 8];
            __builtin_amdgcn_global_load_lds(
                (const __attribute__((address_space(1))) unsigned int*)ga,
                (__attribute__((address_space(3))) unsigned int*)la, 16, 0, 0);
            __builtin_amdgcn_global_load_lds(
                (const __attribute__((address_space(1))) unsigned int*)gb,
                (__attribute__((address_space(3))) unsigned int*)lb, 16, 0, 0);
        }
        __syncthreads();   // compiler drains vmcnt before barrier

        // ---- compute: 2 k-substeps of 32, 16 MFMA each ----
        #pragma unroll
        for (int ks = 0; ks < 2; ks++) {
            // swizzled in-row ushort offset (row&7 == lane&7 for all frags)
            int cswz = ((ks * 64 + lhi * 16) ^ ((lane & 7) << 4)) >> 1;
            short8 af[4], bfr[4];
            #pragma unroll
            for (int m = 0; m < 4; m++) {
                int rowl = wr * 64 + m * 16 + l15;
                af[m] = *(const short8*)&As[rowl * 64 + cswz];
            }
            #pragma unroll
            for (int n = 0; n < 4; n++) {
                int rowl = wc * 64 + n * 16 + l15;
                bfr[n] = *(const short8*)&Bs[rowl * 64 + cswz];
            }
            #pragma unroll
            for (int m = 0; m < 4; m++)
                #pragma unroll
                for (int n = 0; n < 4; n++)
                    acc[m][n] = __builtin_amdgcn_mfma_f32_16x16x32_bf16(
                        af[m], bfr[n], acc[m][n], 0, 0, 0);
        }
        __syncthreads();
    }

    // ---- epilogue: C/D layout col=lane&15, row=(lane>>4)*4+j ----
    #pragma unroll
    for (int m = 0; m < 4; m++) {
        #pragma unroll
        for (int n = 0; n < 4; n++) {
            int gc = n0 + wc * 64 + n * 16 + l15;
            if (gc >= EMB) continue;
            int gr0 = m0 + wr * 64 + m * 16 + lhi * 4;
            #pragma unroll
            for (int j = 0; j < 4; j++) {
                int gr = gr0 + j;
                if (gr < N_NODES) C[(size_t)gr * EMB + gc] = acc[m][n][j];
            }
        }
    }
}

// ---------------- big GCN scatter + finalize ---------------------------------
__global__ void scatter_big(const int* __restrict__ ei, const float* __restrict__ xw,
                            const float* __restrict__ dinv, float* __restrict__ x) {
    int wave = threadIdx.x >> 6, lane = threadIdx.x & 63;
    int base = blockIdx.x * 16 + wave * 4;
    for (int q = 0; q < 4; q++) {
        int e = base + q;
        if (e >= N_EDGES) return;
        int src = ei[e], dst = ei[N_EDGES + e];
        float c = dinv[src] * dinv[dst];
        const float* xr = xw + (size_t)src * EMB;
        float* xd = x + (size_t)dst * EMB;
        for (int k = lane; k < EMB; k += 64) atomicAdd(&xd[k], xr[k] * c);
    }
}
__global__ void finalize_big(const float* __restrict__ xw, const float* __restrict__ dinv,
                             const float* __restrict__ b1, float* __restrict__ x) {
    int wave = threadIdx.x >> 6, lane = threadIdx.x & 63;
    int r = blockIdx.x * 4 + wave;
    if (r >= N_NODES) return;
    float d2 = dinv[r] * dinv[r];
    for (int k = lane; k < EMB; k += 64) {
        float v = x[(size_t)r * EMB + k] + xw[(size_t)r * EMB + k] * d2 + b1[k];
        x[(size_t)r * EMB + k] = fmaxf(v, 0.f);
    }
}

// ---------------- temp = num_feature copy, then row replace ------------------
__global__ void copy_temp(const float* __restrict__ nf, float* __restrict__ temp) {
    size_t i = (size_t)blockIdx.x * blockDim.x + threadIdx.x;
    size_t stride = (size_t)gridDim.x * blockDim.x;
    const float4* src = (const float4*)nf;
    float4* dst = (float4*)temp;
    size_t n4 = (size_t)N_NODES * FEAT / 4;
    for (; i < n4; i += stride) dst[i] = src[i];
}
__global__ void set_rows(const float* __restrict__ x1s, const int* __restrict__ idxbuf,
                         float* __restrict__ temp) {
    int j = blockIdx.x, t = threadIdx.x;
    int r = idxbuf[j];
    for (int k = t; k < FEAT; k += 256)
        temp[(size_t)r * FEAT + k] = x1s[(size_t)(KTOP + j) * FEAT + k];
}

// ---------------- ConvE-ish scoring ------------------------------------------
__global__ void score_kernel(const float* __restrict__ ent, const float* __restrict__ rel,
                             const int* __restrict__ r_idx, const int* __restrict__ e1_idx,
                             const int* __restrict__ e2_idx, const float* __restrict__ conv_w,
                             const float* __restrict__ conv_b, const float* __restrict__ fc_w,
                             const float* __restrict__ fc_b, float* __restrict__ out) {
    __shared__ float cw[24];
    __shared__ float cb[8];
    int t = threadIdx.x;
    if (t < 24) cw[t] = conv_w[t];
    if (t < 8)  cb[t] = conv_b[t];
    __syncthreads();
    int wave = t >> 6, lane = t & 63;
    int b = blockIdx.x * 4 + wave;
    if (b >= BATCH) return;
    const float* r  = rel + (size_t)r_idx[b] * EMB;
    const float* e1 = ent + (size_t)e1_idx[b] * EMB;
    const float* e2 = ent + (size_t)e2_idx[b] * EMB;
    float partial = 0.f;
    for (int p = lane; p < EMB; p += 64) {
        float c0 = r[p], c1 = e1[p], c2 = e2[p];
        for (int g = 0; g < 4; g++) {
            float h0 = c0 * cw[(2 * g) * 3 + 0] + c1 * cw[(2 * g) * 3 + 1] + c2 * cw[(2 * g) * 3 + 2] + cb[2 * g];
            float h1 = c0 * cw[(2 * g + 1) * 3 + 0] + c1 * cw[(2 * g + 1) * 3 + 1] + c2 * cw[(2 * g + 1) * 3 + 2] + cb[2 * g + 1];
            partial += fmaxf(h0, h1) * fc_w[g * EMB + p];
        }
    }
    for (int off = 32; off > 0; off >>= 1) partial += __shfl_down(partial, off, 64);
    if (lane == 0) out[b] = partial + fc_b[0];
}

extern "C" void kernel_launch(void* const* d_in, const int* in_sizes, int n_in,
                              void* d_out, int out_size, void* d_ws, size_t ws_size,
                              hipStream_t stream) {
    const float* num_feature = (const float*)d_in[0];
    const float* anchor      = (const float*)d_in[1];
    const float* Wp          = (const float*)d_in[2];
    const float* bp          = (const float*)d_in[3];
    const float* Wa          = (const float*)d_in[4];
    const float* ba          = (const float*)d_in[5];
    const float* W1          = (const float*)d_in[6];
    const float* b1          = (const float*)d_in[7];
    const float* ent_emb     = (const float*)d_in[8];
    const float* rel_emb     = (const float*)d_in[9];
    const float* conv_w      = (const float*)d_in[10];
    const float* conv_b      = (const float*)d_in[11];
    const float* fc_w        = (const float*)d_in[12];
    const float* fc_b        = (const float*)d_in[13];
    const int*   edge_index  = (const int*)d_in[14];
    const int*   ra_edge     = (const int*)d_in[15];
    const int*   r_idx       = (const int*)d_in[16];
    const int*   e1_idx      = (const int*)d_in[17];
    const int*   e2_idx      = (const int*)d_in[18];

    float* out_score = (float*)d_out;                       // 4096
    float* out_x     = out_score + BATCH;                   // 50500*400
    float* out_temp  = out_x + (size_t)N_NODES * EMB;       // 50500*1000 floats

    // scratch carved out of the temp region (free until copy_temp):
    //   Abf : MP*KP bf16 = 25,886,720 floats
    //   xw  : N_NODES*EMB = 20,200,000 floats
    //   Btbf: NP*KP bf16 = 262,144 floats        total 46,348,864 < 50,500,000
    ushort* Abf  = (ushort*)out_temp;
    float*  xw   = out_temp + (size_t)MP * KP / 2;
    ushort* Btbf = (ushort*)(xw + (size_t)N_NODES * EMB);

    float* ws_f    = (float*)d_ws;
    float* logits  = ws_f;                 // 512
    int*   idxbuf  = (int*)(ws_f + 512);   // 64
    float* probsel = ws_f + 576;           // 64
    float* dinv_s  = ws_f + 640;           // 128
    float* ra      = ws_f + 768;           // 100000
    float* raw     = ws_f + 100768;        // 100000
    float* x1s     = ws_f + 200768;        // 100000
    float* dinv    = ws_f + 300768;        // 50500  -> total 351268 floats

    hipMemsetAsync(d_ws, 0, 351268 * sizeof(float), stream);
    hipMemsetAsync(out_x, 0, (size_t)N_NODES * EMB * sizeof(float), stream);

    logits_kernel<<<RELM1, 256, 0, stream>>>(num_feature, Wp, bp, logits);
    topk_kernel<<<1, 512, 0, stream>>>(logits, idxbuf, probsel);
    build_ra<<<2 * KTOP, 256, 0, stream>>>(anchor, num_feature, idxbuf, probsel, ra);
    gemm_small<<<2 * KTOP, 256, 0, stream>>>(ra, Wa, raw);
    deg_kernel<<<8, 256, 0, stream>>>(ra_edge, 2000, dinv_s);
    dinv_kernel<<<1, 256, 0, stream>>>(dinv_s, 2 * KTOP);
    scatter_small<<<500, 256, 0, stream>>>(ra_edge, raw, dinv_s, x1s);
    finalize_small<<<2 * KTOP, 256, 0, stream>>>(raw, dinv_s, ba, x1s);

    deg_kernel<<<(N_EDGES + 255) / 256, 256, 0, stream>>>(edge_index, N_EDGES, dinv);
    dinv_kernel<<<(N_NODES + 255) / 256, 256, 0, stream>>>(dinv, N_NODES);

    convertA<<<4096, 256, 0, stream>>>(num_feature, Abf);
    convertBt<<<(NP * KP + 255) / 256, 256, 0, stream>>>(W1, Btbf);
    gemm_mfma<<<dim3(MP / 128, NP / 128), 256, 0, stream>>>(Abf, Btbf, xw);

    scatter_big<<<N_EDGES / 16, 256, 0, stream>>>(edge_index, xw, dinv, out_x);
    finalize_big<<<(N_NODES + 3) / 4, 256, 0, stream>>>(xw, dinv, b1, out_x);

    copy_temp<<<4096, 256, 0, stream>>>(num_feature, out_temp);
    set_rows<<<KTOP, 256, 0, stream>>>(x1s, idxbuf, out_temp);

    score_kernel<<<BATCH / 4, 256, 0, stream>>>(ent_emb, rel_emb, r_idx, e1_idx, e2_idx,
                                                conv_w, conv_b, fc_w, fc_b, out_score);
}

// Round 3
// 938.451 us; speedup vs baseline: 2.2953x; 1.4509x over previous
//
#include <hip/hip_runtime.h>
#include <hip/hip_bf16.h>

#define NUM_ENT   50000
#define NUM_RELC  500
#define KTOP      50
#define EMB       400
#define FEAT      1000
#define N_NODES   50500
#define N_EDGES   400000
#define BATCH     4096
#define RELM1     499     // NUM_REL - 1

// padded GEMM dims
#define KP   1024         // FEAT padded to mult of 64
#define MP   50560        // N_NODES padded to 395*128
#define NP   512          // EMB padded to mult of 128

#define NB_SCAN ((N_NODES + 255) / 256)   // 198

typedef __attribute__((ext_vector_type(8))) short short8;
typedef __attribute__((ext_vector_type(4))) float f32x4;

// ---------------- logits: rel_feat @ Wp.T + bp  (499 dots of length 1000) ----
__global__ void logits_kernel(const float* __restrict__ nf, const float* __restrict__ Wp,
                              const float* __restrict__ bp, float* __restrict__ logits) {
    __shared__ float red[256];
    int i = blockIdx.x, t = threadIdx.x;
    float s = 0.f;
    for (int k = t; k < FEAT; k += 256) s += nf[(size_t)i * FEAT + k] * Wp[k];
    red[t] = s; __syncthreads();
    for (int st = 128; st > 0; st >>= 1) { if (t < st) red[t] += red[t + st]; __syncthreads(); }
    if (t == 0) logits[i] = red[0] + bp[0];
}

// ---------------- softmax over 499 + top-50 (sorted ascending) ---------------
__global__ void topk_kernel(const float* __restrict__ logits, int* __restrict__ idxbuf,
                            float* __restrict__ probsel) {
    __shared__ float l[RELM1];
    __shared__ float p[RELM1];
    __shared__ int   flag[RELM1];
    __shared__ float red[512];
    int t = threadIdx.x;  // 512 threads
    float v = (t < RELM1) ? logits[t] : -1e30f;
    if (t < RELM1) l[t] = v;
    red[t] = v; __syncthreads();
    for (int s = 256; s > 0; s >>= 1) { if (t < s) red[t] = fmaxf(red[t], red[t + s]); __syncthreads(); }
    float m = red[0]; __syncthreads();
    float e = (t < RELM1) ? expf(v - m) : 0.f;
    red[t] = e; __syncthreads();
    for (int s = 256; s > 0; s >>= 1) { if (t < s) red[t] += red[t + s]; __syncthreads(); }
    float denom = red[0];
    if (t < RELM1) p[t] = e / denom;
    __syncthreads();
    if (t < RELM1) {
        float lv = l[t]; int cnt = 0;
        for (int j = 0; j < RELM1; j++) {
            float lj = l[j];
            cnt += (lj > lv) || (lj == lv && j < t);
        }
        flag[t] = (cnt < KTOP);
    }
    __syncthreads();
    if (t == 0) {
        int n = 0;
        for (int i = 0; i < RELM1; i++)
            if (flag[i]) { idxbuf[n] = i; probsel[n] = p[i]; n++; }
    }
}

// ---------------- ra = concat(anchor, num_feature[idx]*prob[idx]) ------------
__global__ void build_ra(const float* __restrict__ anchor, const float* __restrict__ nf,
                         const int* __restrict__ idxbuf, const float* __restrict__ probsel,
                         float* __restrict__ ra) {
    int r = blockIdx.x, t = threadIdx.x;
    if (r < KTOP) {
        for (int k = t; k < FEAT; k += 256) ra[r * FEAT + k] = anchor[r * FEAT + k];
    } else {
        int j = r - KTOP; int src = idxbuf[j]; float pp = probsel[j];
        for (int k = t; k < FEAT; k += 256) ra[r * FEAT + k] = nf[(size_t)src * FEAT + k] * pp;
    }
}

// ---------------- raw = ra @ Wa   (100x1000 @ 1000x1000) ---------------------
__global__ void gemm_small(const float* __restrict__ ra, const float* __restrict__ Wa,
                           float* __restrict__ raw) {
    __shared__ float row[FEAT];
    int r = blockIdx.x, t = threadIdx.x;
    for (int k = t; k < FEAT; k += 256) row[k] = ra[r * FEAT + k];
    __syncthreads();
    float a0 = 0.f, a1 = 0.f, a2 = 0.f, a3 = 0.f;
    for (int k = 0; k < FEAT; k++) {
        float rv = row[k];
        const float* wrow = Wa + (size_t)k * FEAT;
        a0 += rv * wrow[t];
        a1 += rv * wrow[t + 256];
        a2 += rv * wrow[t + 512];
        if (t < 232) a3 += rv * wrow[t + 768];
    }
    raw[r * FEAT + t]       = a0;
    raw[r * FEAT + t + 256] = a1;
    raw[r * FEAT + t + 512] = a2;
    if (t < 232) raw[r * FEAT + t + 768] = a3;
}

// ---------------- degree + dinv (small graph, float path) --------------------
__global__ void deg_kernel(const int* __restrict__ ei, int nedges, float* __restrict__ deg) {
    int e = blockIdx.x * 256 + threadIdx.x;
    if (e < nedges) { int dst = ei[nedges + e]; atomicAdd(&deg[dst], 1.0f); }
}
__global__ void dinv_kernel(float* __restrict__ deg, int n) {
    int i = blockIdx.x * 256 + threadIdx.x;
    if (i < n) deg[i] = 1.0f / sqrtf(deg[i] + 1.0f);
}

// ---------------- small GCN scatter + finalize -------------------------------
__global__ void scatter_small(const int* __restrict__ ei, const float* __restrict__ raw,
                              const float* __restrict__ dinv_s, float* __restrict__ acc) {
    int wave = threadIdx.x >> 6, lane = threadIdx.x & 63;
    int e = blockIdx.x * 4 + wave;
    if (e >= 2000) return;
    int src = ei[e], dst = ei[2000 + e];
    float c = dinv_s[src] * dinv_s[dst];
    const float* rs = raw + (size_t)src * FEAT;
    float* ad = acc + (size_t)dst * FEAT;
    for (int k = lane; k < FEAT; k += 64) atomicAdd(&ad[k], rs[k] * c);
}
__global__ void finalize_small(const float* __restrict__ raw, const float* __restrict__ dinv_s,
                               const float* __restrict__ ba, float* __restrict__ x1s) {
    int r = blockIdx.x, t = threadIdx.x;
    float d2 = dinv_s[r] * dinv_s[r];
    for (int k = t; k < FEAT; k += 256) {
        float v = x1s[r * FEAT + k] + raw[r * FEAT + k] * d2 + ba[k];
        x1s[r * FEAT + k] = fmaxf(v, 0.f);
    }
}

// ---------------- big graph: CSR build ---------------------------------------
__global__ void hist_kernel(const int* __restrict__ ei, int* __restrict__ cnt) {
    int e = blockIdx.x * 256 + threadIdx.x;
    if (e < N_EDGES) atomicAdd(&cnt[ei[N_EDGES + e]], 1);
}
__global__ void dinv_from_cnt(const int* __restrict__ cnt, float* __restrict__ dinv) {
    int i = blockIdx.x * 256 + threadIdx.x;
    if (i < N_NODES) dinv[i] = rsqrtf((float)cnt[i] + 1.0f);
}
__global__ void scan_blocks(const int* __restrict__ cnt, int* __restrict__ offs,
                            int* __restrict__ partials) {
    __shared__ int s[256];
    int b = blockIdx.x, t = threadIdx.x;
    int i = b * 256 + t;
    int v = (i < N_NODES) ? cnt[i] : 0;
    s[t] = v; __syncthreads();
    for (int off = 1; off < 256; off <<= 1) {
        int add = (t >= off) ? s[t - off] : 0;
        __syncthreads();
        s[t] += add;
        __syncthreads();
    }
    if (i < N_NODES) offs[i] = s[t] - v;   // exclusive scan within block
    if (t == 255) partials[b] = s[t];
}
__global__ void scan_carry(int* __restrict__ partials) {
    if (threadIdx.x == 0) {
        int run = 0;
        for (int i = 0; i < NB_SCAN; i++) { int v = partials[i]; partials[i] = run; run += v; }
    }
}
__global__ void scan_add(int* __restrict__ offs, const int* __restrict__ partials) {
    int b = blockIdx.x; int i = b * 256 + threadIdx.x;
    if (i < N_NODES) offs[i] += partials[b];
}
__global__ void fill_csr(const int* __restrict__ ei, const int* __restrict__ offs,
                         int* __restrict__ cursor, const float* __restrict__ dinv,
                         int* __restrict__ esrc, float* __restrict__ ecoef) {
    int e = blockIdx.x * 256 + threadIdx.x;
    if (e >= N_EDGES) return;
    int src = ei[e], dst = ei[N_EDGES + e];
    int pos = offs[dst] + atomicAdd(&cursor[dst], 1);
    esrc[pos] = src;
    ecoef[pos] = dinv[src] * dinv[dst];
}

// ---------------- bf16 conversion: A = num_feature -> [MP][KP] bf16 ----------
__global__ void convertA(const float* __restrict__ nf, ushort* __restrict__ Abf) {
    size_t idx = (size_t)blockIdx.x * 256 + threadIdx.x;
    size_t stride = (size_t)gridDim.x * 256;
    size_t total = (size_t)MP * KP / 8;     // 8 bf16 per thread-chunk
    for (; idx < total; idx += stride) {
        int row = (int)(idx >> 7);          // KP/8 = 128 chunks per row
        int kb  = (int)(idx & 127);
        ushort v[8];
        if (row < N_NODES && kb < 125) {    // 125*8 = 1000 = FEAT
            const float* src = nf + (size_t)row * FEAT + kb * 8;
            #pragma unroll
            for (int j = 0; j < 8; j++) {
                __hip_bfloat16 h = __float2bfloat16(src[j]);
                v[j] = *(ushort*)&h;
            }
        } else {
            #pragma unroll
            for (int j = 0; j < 8; j++) v[j] = 0;
        }
        *(uint4*)&Abf[idx * 8] = *(uint4*)v;
    }
}

// ---------------- bf16 conversion: Bt[n][k] = W1[k][n] -> [NP][KP] bf16 ------
__global__ void convertBt(const float* __restrict__ W1, ushort* __restrict__ Btbf) {
    int idx = blockIdx.x * 256 + threadIdx.x;  // NP*KP = 524288 total
    if (idx >= NP * KP) return;
    int n = idx >> 10;       // /KP
    int k = idx & 1023;
    ushort out = 0;
    if (n < EMB && k < FEAT) {
        __hip_bfloat16 h = __float2bfloat16(W1[(size_t)k * EMB + n]);
        out = *(ushort*)&h;
    }
    Btbf[idx] = out;
}

// ---------------- MFMA GEMM: xw = A(bf16) @ Bt(bf16)^T  [MPxKP]x[NPxKP]^T ----
// 128x128 tile, BK=64, 4 waves (2x2), global_load_lds + XOR-swizzled LDS.
__global__ __launch_bounds__(256) void gemm_mfma(const ushort* __restrict__ A,
                                                 const ushort* __restrict__ Bt,
                                                 float* __restrict__ C) {
    __shared__ ushort As[128 * 64];   // 16 KB, swizzled rows of 64 ushorts (128B)
    __shared__ ushort Bs[128 * 64];   // 16 KB
    int t = threadIdx.x;
    int m0 = blockIdx.x * 128;
    int n0 = blockIdx.y * 128;

    int srow = t >> 3;                     // 0..31
    int kbx  = (t & 7) ^ (srow & 7);       // involution within 8-row stripe

    int lane = t & 63;
    int wv   = t >> 6;
    int wr   = wv >> 1, wc = wv & 1;       // wave -> 64x64 quadrant
    int l15  = lane & 15, lhi = lane >> 4;

    f32x4 acc[4][4];
    #pragma unroll
    for (int m = 0; m < 4; m++)
        #pragma unroll
        for (int n = 0; n < 4; n++) acc[m][n] = (f32x4){0.f, 0.f, 0.f, 0.f};

    for (int kt = 0; kt < KP / 64; kt++) {
        int k0 = kt * 64;
        #pragma unroll
        for (int r = 0; r < 4; r++) {
            int row = r * 32 + srow;
            const ushort* ga = A  + (size_t)(m0 + row) * KP + k0 + kbx * 8;
            const ushort* gb = Bt + (size_t)(n0 + row) * KP + k0 + kbx * 8;
            ushort* la = &As[(size_t)row * 64 + (t & 7) * 8];
            ushort* lb = &Bs[(size_t)row * 64 + (t & 7) * 8];
            __builtin_amdgcn_global_load_lds(
                (const __attribute__((address_space(1))) unsigned int*)ga,
                (__attribute__((address_space(3))) unsigned int*)la, 16, 0, 0);
            __builtin_amdgcn_global_load_lds(
                (const __attribute__((address_space(1))) unsigned int*)gb,
                (__attribute__((address_space(3))) unsigned int*)lb, 16, 0, 0);
        }
        __syncthreads();

        #pragma unroll
        for (int ks = 0; ks < 2; ks++) {
            int cswz = ((ks * 64 + lhi * 16) ^ ((lane & 7) << 4)) >> 1;
            short8 af[4], bfr[4];
            #pragma unroll
            for (int m = 0; m < 4; m++) {
                int rowl = wr * 64 + m * 16 + l15;
                af[m] = *(const short8*)&As[rowl * 64 + cswz];
            }
            #pragma unroll
            for (int n = 0; n < 4; n++) {
                int rowl = wc * 64 + n * 16 + l15;
                bfr[n] = *(const short8*)&Bs[rowl * 64 + cswz];
            }
            #pragma unroll
            for (int m = 0; m < 4; m++)
                #pragma unroll
                for (int n = 0; n < 4; n++)
                    acc[m][n] = __builtin_amdgcn_mfma_f32_16x16x32_bf16(
                        af[m], bfr[n], acc[m][n], 0, 0, 0);
        }
        __syncthreads();
    }

    #pragma unroll
    for (int m = 0; m < 4; m++) {
        #pragma unroll
        for (int n = 0; n < 4; n++) {
            int gc = n0 + wc * 64 + n * 16 + l15;
            if (gc >= EMB) continue;
            int gr0 = m0 + wr * 64 + m * 16 + lhi * 4;
            #pragma unroll
            for (int j = 0; j < 4; j++) {
                int gr = gr0 + j;
                if (gr < N_NODES) C[(size_t)gr * EMB + gc] = acc[m][n][j];
            }
        }
    }
}

// ---------------- big GCN: pull-gather + fused finalize (relu/bias) ----------
__global__ __launch_bounds__(256) void gather_big(const int* __restrict__ esrc,
                                                  const float* __restrict__ ecoef,
                                                  const int* __restrict__ offs,
                                                  const int* __restrict__ cnt,
                                                  const float* __restrict__ xw,
                                                  const float* __restrict__ dinv,
                                                  const float* __restrict__ b1,
                                                  float* __restrict__ x) {
    int wave = threadIdx.x >> 6, lane = threadIdx.x & 63;
    int dst = blockIdx.x * 4 + wave;
    if (dst >= N_NODES) return;
    int start = offs[dst], deg = cnt[dst];
    float acc[7] = {};
    for (int j = 0; j < deg; j++) {
        int src = esrc[start + j];
        float c = ecoef[start + j];
        const float* xr = xw + (size_t)src * EMB;
        #pragma unroll
        for (int q = 0; q < 7; q++) {
            int k = lane + q * 64;
            if (k < EMB) acc[q] += xr[k] * c;
        }
    }
    float d2 = dinv[dst] * dinv[dst];
    const float* xs = xw + (size_t)dst * EMB;
    float* xo = x + (size_t)dst * EMB;
    #pragma unroll
    for (int q = 0; q < 7; q++) {
        int k = lane + q * 64;
        if (k < EMB) xo[k] = fmaxf(acc[q] + xs[k] * d2 + b1[k], 0.f);
    }
}

// ---------------- temp = num_feature copy, then row replace ------------------
__global__ void copy_temp(const float* __restrict__ nf, float* __restrict__ temp) {
    size_t i = (size_t)blockIdx.x * blockDim.x + threadIdx.x;
    size_t stride = (size_t)gridDim.x * blockDim.x;
    const float4* src = (const float4*)nf;
    float4* dst = (float4*)temp;
    size_t n4 = (size_t)N_NODES * FEAT / 4;
    for (; i < n4; i += stride) dst[i] = src[i];
}
__global__ void set_rows(const float* __restrict__ x1s, const int* __restrict__ idxbuf,
                         float* __restrict__ temp) {
    int j = blockIdx.x, t = threadIdx.x;
    int r = idxbuf[j];
    for (int k = t; k < FEAT; k += 256)
        temp[(size_t)r * FEAT + k] = x1s[(size_t)(KTOP + j) * FEAT + k];
}

// ---------------- ConvE-ish scoring ------------------------------------------
__global__ void score_kernel(const float* __restrict__ ent, const float* __restrict__ rel,
                             const int* __restrict__ r_idx, const int* __restrict__ e1_idx,
                             const int* __restrict__ e2_idx, const float* __restrict__ conv_w,
                             const float* __restrict__ conv_b, const float* __restrict__ fc_w,
                             const float* __restrict__ fc_b, float* __restrict__ out) {
    __shared__ float cw[24];
    __shared__ float cb[8];
    int t = threadIdx.x;
    if (t < 24) cw[t] = conv_w[t];
    if (t < 8)  cb[t] = conv_b[t];
    __syncthreads();
    int wave = t >> 6, lane = t & 63;
    int b = blockIdx.x * 4 + wave;
    if (b >= BATCH) return;
    const float* r  = rel + (size_t)r_idx[b] * EMB;
    const float* e1 = ent + (size_t)e1_idx[b] * EMB;
    const float* e2 = ent + (size_t)e2_idx[b] * EMB;
    float partial = 0.f;
    for (int p = lane; p < EMB; p += 64) {
        float c0 = r[p], c1 = e1[p], c2 = e2[p];
        for (int g = 0; g < 4; g++) {
            float h0 = c0 * cw[(2 * g) * 3 + 0] + c1 * cw[(2 * g) * 3 + 1] + c2 * cw[(2 * g) * 3 + 2] + cb[2 * g];
            float h1 = c0 * cw[(2 * g + 1) * 3 + 0] + c1 * cw[(2 * g + 1) * 3 + 1] + c2 * cw[(2 * g + 1) * 3 + 2] + cb[2 * g + 1];
            partial += fmaxf(h0, h1) * fc_w[g * EMB + p];
        }
    }
    for (int off = 32; off > 0; off >>= 1) partial += __shfl_down(partial, off, 64);
    if (lane == 0) out[b] = partial + fc_b[0];
}

extern "C" void kernel_launch(void* const* d_in, const int* in_sizes, int n_in,
                              void* d_out, int out_size, void* d_ws, size_t ws_size,
                              hipStream_t stream) {
    const float* num_feature = (const float*)d_in[0];
    const float* anchor      = (const float*)d_in[1];
    const float* Wp          = (const float*)d_in[2];
    const float* bp          = (const float*)d_in[3];
    const float* Wa          = (const float*)d_in[4];
    const float* ba          = (const float*)d_in[5];
    const float* W1          = (const float*)d_in[6];
    const float* b1          = (const float*)d_in[7];
    const float* ent_emb     = (const float*)d_in[8];
    const float* rel_emb     = (const float*)d_in[9];
    const float* conv_w      = (const float*)d_in[10];
    const float* conv_b      = (const float*)d_in[11];
    const float* fc_w        = (const float*)d_in[12];
    const float* fc_b        = (const float*)d_in[13];
    const int*   edge_index  = (const int*)d_in[14];
    const int*   ra_edge     = (const int*)d_in[15];
    const int*   r_idx       = (const int*)d_in[16];
    const int*   e1_idx      = (const int*)d_in[17];
    const int*   e2_idx      = (const int*)d_in[18];

    float* out_score = (float*)d_out;                       // 4096
    float* out_x     = out_score + BATCH;                   // 50500*400
    float* out_temp  = out_x + (size_t)N_NODES * EMB;       // 50500*1000 floats

    // scratch carved out of the temp region (free until copy_temp):
    ushort* Abf  = (ushort*)out_temp;                        // MP*KP bf16
    float*  xw   = out_temp + (size_t)MP * KP / 2;           // N_NODES*EMB f32
    ushort* Btbf = (ushort*)(xw + (size_t)N_NODES * EMB);    // NP*KP bf16
    float*  tailf = (float*)Btbf + (size_t)NP * KP / 2;      // CSR tail (~0.95M floats)
    int*   cnt      = (int*)tailf;
    int*   cursor   = cnt + N_NODES;
    int*   offs     = cursor + N_NODES;
    int*   partials = offs + N_NODES;
    int*   esrc     = partials + 256;
    float* ecoef    = (float*)(esrc + N_EDGES);

    float* ws_f    = (float*)d_ws;
    float* logits  = ws_f;                 // 512
    int*   idxbuf  = (int*)(ws_f + 512);   // 64
    float* probsel = ws_f + 576;           // 64
    float* dinv_s  = ws_f + 640;           // 128
    float* ra      = ws_f + 768;           // 100000
    float* raw     = ws_f + 100768;        // 100000
    float* x1s     = ws_f + 200768;        // 100000
    float* dinv    = ws_f + 300768;        // 50500  -> total 351268 floats

    hipMemsetAsync(d_ws, 0, 351268 * sizeof(float), stream);
    hipMemsetAsync(cnt, 0, 2 * N_NODES * sizeof(int), stream);   // cnt + cursor

    // ---- small GCN pipeline ----
    logits_kernel<<<RELM1, 256, 0, stream>>>(num_feature, Wp, bp, logits);
    topk_kernel<<<1, 512, 0, stream>>>(logits, idxbuf, probsel);
    build_ra<<<2 * KTOP, 256, 0, stream>>>(anchor, num_feature, idxbuf, probsel, ra);
    gemm_small<<<2 * KTOP, 256, 0, stream>>>(ra, Wa, raw);
    deg_kernel<<<8, 256, 0, stream>>>(ra_edge, 2000, dinv_s);
    dinv_kernel<<<1, 256, 0, stream>>>(dinv_s, 2 * KTOP);
    scatter_small<<<500, 256, 0, stream>>>(ra_edge, raw, dinv_s, x1s);
    finalize_small<<<2 * KTOP, 256, 0, stream>>>(raw, dinv_s, ba, x1s);

    // ---- big graph CSR build ----
    hist_kernel<<<(N_EDGES + 255) / 256, 256, 0, stream>>>(edge_index, cnt);
    dinv_from_cnt<<<NB_SCAN, 256, 0, stream>>>(cnt, dinv);
    scan_blocks<<<NB_SCAN, 256, 0, stream>>>(cnt, offs, partials);
    scan_carry<<<1, 64, 0, stream>>>(partials);
    scan_add<<<NB_SCAN, 256, 0, stream>>>(offs, partials);
    fill_csr<<<(N_EDGES + 255) / 256, 256, 0, stream>>>(edge_index, offs, cursor, dinv,
                                                        esrc, ecoef);

    // ---- big GEMM (bf16 MFMA) ----
    convertA<<<4096, 256, 0, stream>>>(num_feature, Abf);
    convertBt<<<(NP * KP + 255) / 256, 256, 0, stream>>>(W1, Btbf);
    gemm_mfma<<<dim3(MP / 128, NP / 128), 256, 0, stream>>>(Abf, Btbf, xw);

    // ---- aggregation (pull) with fused bias+relu ----
    gather_big<<<(N_NODES + 3) / 4, 256, 0, stream>>>(esrc, ecoef, offs, cnt, xw, dinv,
                                                      b1, out_x);

    // ---- temp output ----
    copy_temp<<<4096, 256, 0, stream>>>(num_feature, out_temp);
    set_rows<<<KTOP, 256, 0, stream>>>(x1s, idxbuf, out_temp);

    // ---- scoring ----
    score_kernel<<<BATCH / 4, 256, 0, stream>>>(ent_emb, rel_emb, r_idx, e1_idx, e2_idx,
                                                conv_w, conv_b, fc_w, fc_b, out_score);
}

// Round 4
// 534.545 us; speedup vs baseline: 4.0296x; 1.7556x over previous
//
#include <hip/hip_runtime.h>
#include <hip/hip_bf16.h>

#define NUM_ENT   50000
#define NUM_RELC  500
#define KTOP      50
#define EMB       400
#define FEAT      1000
#define N_NODES   50500
#define N_EDGES   400000
#define BATCH     4096
#define RELM1     499     // NUM_REL - 1

// padded GEMM dims
#define KP   1024         // FEAT padded to mult of 64
#define MP   50560        // N_NODES padded to 395*128
#define NP   512          // EMB padded to mult of 128

#define NB_SCAN ((N_NODES + 255) / 256)   // 198

typedef __attribute__((ext_vector_type(8))) short short8;
typedef __attribute__((ext_vector_type(4))) float f32x4;

// ---------------- logits: rel_feat @ Wp.T + bp  (499 dots of length 1000) ----
__global__ void logits_kernel(const float* __restrict__ nf, const float* __restrict__ Wp,
                              const float* __restrict__ bp, float* __restrict__ logits) {
    __shared__ float red[256];
    int i = blockIdx.x, t = threadIdx.x;
    float s = 0.f;
    for (int k = t; k < FEAT; k += 256) s += nf[(size_t)i * FEAT + k] * Wp[k];
    red[t] = s; __syncthreads();
    for (int st = 128; st > 0; st >>= 1) { if (t < st) red[t] += red[t + st]; __syncthreads(); }
    if (t == 0) logits[i] = red[0] + bp[0];
}

// ---------------- softmax over 499 + top-50 (sorted ascending) ---------------
__global__ void topk_kernel(const float* __restrict__ logits, int* __restrict__ idxbuf,
                            float* __restrict__ probsel) {
    __shared__ float l[RELM1];
    __shared__ float p[RELM1];
    __shared__ int   flag[RELM1];
    __shared__ float red[512];
    int t = threadIdx.x;  // 512 threads
    float v = (t < RELM1) ? logits[t] : -1e30f;
    if (t < RELM1) l[t] = v;
    red[t] = v; __syncthreads();
    for (int s = 256; s > 0; s >>= 1) { if (t < s) red[t] = fmaxf(red[t], red[t + s]); __syncthreads(); }
    float m = red[0]; __syncthreads();
    float e = (t < RELM1) ? expf(v - m) : 0.f;
    red[t] = e; __syncthreads();
    for (int s = 256; s > 0; s >>= 1) { if (t < s) red[t] += red[t + s]; __syncthreads(); }
    float denom = red[0];
    if (t < RELM1) p[t] = e / denom;
    __syncthreads();
    if (t < RELM1) {
        float lv = l[t]; int cnt = 0;
        for (int j = 0; j < RELM1; j++) {
            float lj = l[j];
            cnt += (lj > lv) || (lj == lv && j < t);
        }
        flag[t] = (cnt < KTOP);
    }
    __syncthreads();
    if (t == 0) {
        int n = 0;
        for (int i = 0; i < RELM1; i++)
            if (flag[i]) { idxbuf[n] = i; probsel[n] = p[i]; n++; }
    }
}

// ---------------- ra = concat(anchor, num_feature[idx]*prob[idx]) ------------
__global__ void build_ra(const float* __restrict__ anchor, const float* __restrict__ nf,
                         const int* __restrict__ idxbuf, const float* __restrict__ probsel,
                         float* __restrict__ ra) {
    int r = blockIdx.x, t = threadIdx.x;
    if (r < KTOP) {
        for (int k = t; k < FEAT; k += 256) ra[r * FEAT + k] = anchor[r * FEAT + k];
    } else {
        int j = r - KTOP; int src = idxbuf[j]; float pp = probsel[j];
        for (int k = t; k < FEAT; k += 256) ra[r * FEAT + k] = nf[(size_t)src * FEAT + k] * pp;
    }
}

// ---------------- degree + dinv (small graph, float path) --------------------
__global__ void deg_kernel(const int* __restrict__ ei, int nedges, float* __restrict__ deg) {
    int e = blockIdx.x * 256 + threadIdx.x;
    if (e < nedges) { int dst = ei[nedges + e]; atomicAdd(&deg[dst], 1.0f); }
}
__global__ void dinv_kernel(float* __restrict__ deg, int n) {
    int i = blockIdx.x * 256 + threadIdx.x;
    if (i < n) deg[i] = 1.0f / sqrtf(deg[i] + 1.0f);
}

// ---------------- small GCN scatter + finalize -------------------------------
__global__ void scatter_small(const int* __restrict__ ei, const float* __restrict__ raw,
                              const float* __restrict__ dinv_s, float* __restrict__ acc) {
    int wave = threadIdx.x >> 6, lane = threadIdx.x & 63;
    int e = blockIdx.x * 4 + wave;
    if (e >= 2000) return;
    int src = ei[e], dst = ei[2000 + e];
    float c = dinv_s[src] * dinv_s[dst];
    const float* rs = raw + (size_t)src * FEAT;
    float* ad = acc + (size_t)dst * FEAT;
    for (int k = lane; k < FEAT; k += 64) atomicAdd(&ad[k], rs[k] * c);
}
__global__ void finalize_small(const float* __restrict__ raw, const float* __restrict__ dinv_s,
                               const float* __restrict__ ba, float* __restrict__ x1s) {
    int r = blockIdx.x, t = threadIdx.x;
    float d2 = dinv_s[r] * dinv_s[r];
    for (int k = t; k < FEAT; k += 256) {
        float v = x1s[r * FEAT + k] + raw[r * FEAT + k] * d2 + ba[k];
        x1s[r * FEAT + k] = fmaxf(v, 0.f);
    }
}

// ---------------- big graph: CSR build ---------------------------------------
__global__ void hist_kernel(const int* __restrict__ ei, int* __restrict__ cnt) {
    int e = blockIdx.x * 256 + threadIdx.x;
    if (e < N_EDGES) atomicAdd(&cnt[ei[N_EDGES + e]], 1);
}
__global__ void dinv_from_cnt(const int* __restrict__ cnt, float* __restrict__ dinv) {
    int i = blockIdx.x * 256 + threadIdx.x;
    if (i < N_NODES) dinv[i] = rsqrtf((float)cnt[i] + 1.0f);
}
__global__ void scan_blocks(const int* __restrict__ cnt, int* __restrict__ offs,
                            int* __restrict__ partials) {
    __shared__ int s[256];
    int b = blockIdx.x, t = threadIdx.x;
    int i = b * 256 + t;
    int v = (i < N_NODES) ? cnt[i] : 0;
    s[t] = v; __syncthreads();
    for (int off = 1; off < 256; off <<= 1) {
        int add = (t >= off) ? s[t - off] : 0;
        __syncthreads();
        s[t] += add;
        __syncthreads();
    }
    if (i < N_NODES) offs[i] = s[t] - v;   // exclusive scan within block
    if (t == 255) partials[b] = s[t];
}
__global__ void scan_carry(int* __restrict__ partials) {
    if (threadIdx.x == 0) {
        int run = 0;
        for (int i = 0; i < NB_SCAN; i++) { int v = partials[i]; partials[i] = run; run += v; }
    }
}
__global__ void scan_add(int* __restrict__ offs, const int* __restrict__ partials) {
    int b = blockIdx.x; int i = b * 256 + threadIdx.x;
    if (i < N_NODES) offs[i] += partials[b];
}
__global__ void fill_csr(const int* __restrict__ ei, const int* __restrict__ offs,
                         int* __restrict__ cursor, const float* __restrict__ dinv,
                         int* __restrict__ esrc, float* __restrict__ ecoef) {
    int e = blockIdx.x * 256 + threadIdx.x;
    if (e >= N_EDGES) return;
    int src = ei[e], dst = ei[N_EDGES + e];
    int pos = offs[dst] + atomicAdd(&cursor[dst], 1);
    esrc[pos] = src;
    ecoef[pos] = dinv[src] * dinv[dst];
}

// ---------------- bf16 conversion: A = num_feature -> [MP][KP] bf16 ----------
__global__ void convertA(const float* __restrict__ nf, ushort* __restrict__ Abf) {
    size_t idx = (size_t)blockIdx.x * 256 + threadIdx.x;
    size_t stride = (size_t)gridDim.x * 256;
    size_t total = (size_t)MP * KP / 8;     // 8 bf16 per thread-chunk
    for (; idx < total; idx += stride) {
        int row = (int)(idx >> 7);          // KP/8 = 128 chunks per row
        int kb  = (int)(idx & 127);
        ushort v[8];
        if (row < N_NODES && kb < 125) {    // 125*8 = 1000 = FEAT
            const float* src = nf + (size_t)row * FEAT + kb * 8;
            #pragma unroll
            for (int j = 0; j < 8; j++) {
                __hip_bfloat16 h = __float2bfloat16(src[j]);
                v[j] = *(ushort*)&h;
            }
        } else {
            #pragma unroll
            for (int j = 0; j < 8; j++) v[j] = 0;
        }
        *(uint4*)&Abf[idx * 8] = *(uint4*)v;
    }
}

// ---------------- ra (100x1000 f32) -> rabf [128][KP] bf16 -------------------
__global__ void convert_rabf(const float* __restrict__ ra, ushort* __restrict__ rabf) {
    int idx = blockIdx.x * 256 + threadIdx.x;   // 128*KP/8 = 16384 chunks
    if (idx >= 128 * KP / 8) return;
    int row = idx >> 7;
    int kb  = idx & 127;
    ushort v[8];
    if (row < 2 * KTOP && kb < 125) {
        const float* src = ra + (size_t)row * FEAT + kb * 8;
        #pragma unroll
        for (int j = 0; j < 8; j++) {
            __hip_bfloat16 h = __float2bfloat16(src[j]);
            v[j] = *(ushort*)&h;
        }
    } else {
        #pragma unroll
        for (int j = 0; j < 8; j++) v[j] = 0;
    }
    *(uint4*)&rabf[idx * 8] = *(uint4*)v;
}

// ---------------- LDS-tiled transpose-convert: dst[n][KP] = bf16(src[k][n]) --
// src is [K][N] f32 row-major; dst is [Npad][KP] bf16, zero-padded.
// grid: (ceil(Kpad/64), ceil(Npad/64)), 256 threads.
__global__ void transpose_bf16(const float* __restrict__ src, int K, int N,
                               ushort* __restrict__ dst) {
    __shared__ float tile[64][65];
    int k0 = blockIdx.x * 64, n0 = blockIdx.y * 64;
    int tx = threadIdx.x & 63, ty = threadIdx.x >> 6;   // 64 x 4
    for (int i = ty; i < 64; i += 4) {
        int k = k0 + i, n = n0 + tx;
        tile[i][tx] = (k < K && n < N) ? src[(size_t)k * N + n] : 0.f;
    }
    __syncthreads();
    for (int i = ty; i < 64; i += 4) {
        int n = n0 + i, k = k0 + tx;
        __hip_bfloat16 h = __float2bfloat16(tile[tx][i]);
        dst[(size_t)n * KP + k] = *(ushort*)&h;
    }
}

// ---------------- MFMA GEMM: C[M][ldc] = A(bf16,[*][KP]) @ Bt(bf16,[*][KP])^T
// 128x128 tile, BK=64, 4 waves (2x2), global_load_lds + XOR-swizzled LDS.
__global__ __launch_bounds__(256) void gemm_mfma(const ushort* __restrict__ A,
                                                 const ushort* __restrict__ Bt,
                                                 float* __restrict__ C,
                                                 int M, int N, int ldc) {
    __shared__ ushort As[128 * 64];   // 16 KB, swizzled rows of 64 ushorts (128B)
    __shared__ ushort Bs[128 * 64];   // 16 KB
    int t = threadIdx.x;
    int m0 = blockIdx.x * 128;
    int n0 = blockIdx.y * 128;

    int srow = t >> 3;                     // 0..31
    int kbx  = (t & 7) ^ (srow & 7);       // involution within 8-row stripe

    int lane = t & 63;
    int wv   = t >> 6;
    int wr   = wv >> 1, wc = wv & 1;       // wave -> 64x64 quadrant
    int l15  = lane & 15, lhi = lane >> 4;

    f32x4 acc[4][4];
    #pragma unroll
    for (int m = 0; m < 4; m++)
        #pragma unroll
        for (int n = 0; n < 4; n++) acc[m][n] = (f32x4){0.f, 0.f, 0.f, 0.f};

    for (int kt = 0; kt < KP / 64; kt++) {
        int k0 = kt * 64;
        #pragma unroll
        for (int r = 0; r < 4; r++) {
            int row = r * 32 + srow;
            const ushort* ga = A  + (size_t)(m0 + row) * KP + k0 + kbx * 8;
            const ushort* gb = Bt + (size_t)(n0 + row) * KP + k0 + kbx * 8;
            ushort* la = &As[(size_t)row * 64 + (t & 7) * 8];
            ushort* lb = &Bs[(size_t)row * 64 + (t & 7) * 8];
            __builtin_amdgcn_global_load_lds(
                (const __attribute__((address_space(1))) unsigned int*)ga,
                (__attribute__((address_space(3))) unsigned int*)la, 16, 0, 0);
            __builtin_amdgcn_global_load_lds(
                (const __attribute__((address_space(1))) unsigned int*)gb,
                (__attribute__((address_space(3))) unsigned int*)lb, 16, 0, 0);
        }
        __syncthreads();

        #pragma unroll
        for (int ks = 0; ks < 2; ks++) {
            int cswz = ((ks * 64 + lhi * 16) ^ ((lane & 7) << 4)) >> 1;
            short8 af[4], bfr[4];
            #pragma unroll
            for (int m = 0; m < 4; m++) {
                int rowl = wr * 64 + m * 16 + l15;
                af[m] = *(const short8*)&As[rowl * 64 + cswz];
            }
            #pragma unroll
            for (int n = 0; n < 4; n++) {
                int rowl = wc * 64 + n * 16 + l15;
                bfr[n] = *(const short8*)&Bs[rowl * 64 + cswz];
            }
            #pragma unroll
            for (int m = 0; m < 4; m++)
                #pragma unroll
                for (int n = 0; n < 4; n++)
                    acc[m][n] = __builtin_amdgcn_mfma_f32_16x16x32_bf16(
                        af[m], bfr[n], acc[m][n], 0, 0, 0);
        }
        __syncthreads();
    }

    #pragma unroll
    for (int m = 0; m < 4; m++) {
        #pragma unroll
        for (int n = 0; n < 4; n++) {
            int gc = n0 + wc * 64 + n * 16 + l15;
            if (gc >= N) continue;
            int gr0 = m0 + wr * 64 + m * 16 + lhi * 4;
            #pragma unroll
            for (int j = 0; j < 4; j++) {
                int gr = gr0 + j;
                if (gr < M) C[(size_t)gr * ldc + gc] = acc[m][n][j];
            }
        }
    }
}

// ---------------- big GCN: pull-gather + fused finalize (relu/bias) ----------
__global__ __launch_bounds__(256) void gather_big(const int* __restrict__ esrc,
                                                  const float* __restrict__ ecoef,
                                                  const int* __restrict__ offs,
                                                  const int* __restrict__ cnt,
                                                  const float* __restrict__ xw,
                                                  const float* __restrict__ dinv,
                                                  const float* __restrict__ b1,
                                                  float* __restrict__ x) {
    int wave = threadIdx.x >> 6, lane = threadIdx.x & 63;
    int dst = blockIdx.x * 4 + wave;
    if (dst >= N_NODES) return;
    int start = offs[dst], deg = cnt[dst];
    float acc[7] = {};
    for (int j = 0; j < deg; j++) {
        int src = esrc[start + j];
        float c = ecoef[start + j];
        const float* xr = xw + (size_t)src * EMB;
        #pragma unroll
        for (int q = 0; q < 7; q++) {
            int k = lane + q * 64;
            if (k < EMB) acc[q] += xr[k] * c;
        }
    }
    float d2 = dinv[dst] * dinv[dst];
    const float* xs = xw + (size_t)dst * EMB;
    float* xo = x + (size_t)dst * EMB;
    #pragma unroll
    for (int q = 0; q < 7; q++) {
        int k = lane + q * 64;
        if (k < EMB) xo[k] = fmaxf(acc[q] + xs[k] * d2 + b1[k], 0.f);
    }
}

// ---------------- temp = num_feature copy, then row replace ------------------
__global__ void copy_temp(const float* __restrict__ nf, float* __restrict__ temp) {
    size_t i = (size_t)blockIdx.x * blockDim.x + threadIdx.x;
    size_t stride = (size_t)gridDim.x * blockDim.x;
    const float4* src = (const float4*)nf;
    float4* dst = (float4*)temp;
    size_t n4 = (size_t)N_NODES * FEAT / 4;
    for (; i < n4; i += stride) dst[i] = src[i];
}
__global__ void set_rows(const float* __restrict__ x1s, const int* __restrict__ idxbuf,
                         float* __restrict__ temp) {
    int j = blockIdx.x, t = threadIdx.x;
    int r = idxbuf[j];
    for (int k = t; k < FEAT; k += 256)
        temp[(size_t)r * FEAT + k] = x1s[(size_t)(KTOP + j) * FEAT + k];
}

// ---------------- ConvE-ish scoring ------------------------------------------
__global__ void score_kernel(const float* __restrict__ ent, const float* __restrict__ rel,
                             const int* __restrict__ r_idx, const int* __restrict__ e1_idx,
                             const int* __restrict__ e2_idx, const float* __restrict__ conv_w,
                             const float* __restrict__ conv_b, const float* __restrict__ fc_w,
                             const float* __restrict__ fc_b, float* __restrict__ out) {
    __shared__ float cw[24];
    __shared__ float cb[8];
    int t = threadIdx.x;
    if (t < 24) cw[t] = conv_w[t];
    if (t < 8)  cb[t] = conv_b[t];
    __syncthreads();
    int wave = t >> 6, lane = t & 63;
    int b = blockIdx.x * 4 + wave;
    if (b >= BATCH) return;
    const float* r  = rel + (size_t)r_idx[b] * EMB;
    const float* e1 = ent + (size_t)e1_idx[b] * EMB;
    const float* e2 = ent + (size_t)e2_idx[b] * EMB;
    float partial = 0.f;
    for (int p = lane; p < EMB; p += 64) {
        float c0 = r[p], c1 = e1[p], c2 = e2[p];
        for (int g = 0; g < 4; g++) {
            float h0 = c0 * cw[(2 * g) * 3 + 0] + c1 * cw[(2 * g) * 3 + 1] + c2 * cw[(2 * g) * 3 + 2] + cb[2 * g];
            float h1 = c0 * cw[(2 * g + 1) * 3 + 0] + c1 * cw[(2 * g + 1) * 3 + 1] + c2 * cw[(2 * g + 1) * 3 + 2] + cb[2 * g + 1];
            partial += fmaxf(h0, h1) * fc_w[g * EMB + p];
        }
    }
    for (int off = 32; off > 0; off >>= 1) partial += __shfl_down(partial, off, 64);
    if (lane == 0) out[b] = partial + fc_b[0];
}

extern "C" void kernel_launch(void* const* d_in, const int* in_sizes, int n_in,
                              void* d_out, int out_size, void* d_ws, size_t ws_size,
                              hipStream_t stream) {
    const float* num_feature = (const float*)d_in[0];
    const float* anchor      = (const float*)d_in[1];
    const float* Wp          = (const float*)d_in[2];
    const float* bp          = (const float*)d_in[3];
    const float* Wa          = (const float*)d_in[4];
    const float* ba          = (const float*)d_in[5];
    const float* W1          = (const float*)d_in[6];
    const float* b1          = (const float*)d_in[7];
    const float* ent_emb     = (const float*)d_in[8];
    const float* rel_emb     = (const float*)d_in[9];
    const float* conv_w      = (const float*)d_in[10];
    const float* conv_b      = (const float*)d_in[11];
    const float* fc_w        = (const float*)d_in[12];
    const float* fc_b        = (const float*)d_in[13];
    const int*   edge_index  = (const int*)d_in[14];
    const int*   ra_edge     = (const int*)d_in[15];
    const int*   r_idx       = (const int*)d_in[16];
    const int*   e1_idx      = (const int*)d_in[17];
    const int*   e2_idx      = (const int*)d_in[18];

    float* out_score = (float*)d_out;                       // 4096
    float* out_x     = out_score + BATCH;                   // 50500*400
    float* out_temp  = out_x + (size_t)N_NODES * EMB;       // 50500*1000 floats

    // scratch carved out of the temp region (free until copy_temp):
    ushort* Abf  = (ushort*)out_temp;                        // MP*KP bf16
    float*  xw   = out_temp + (size_t)MP * KP / 2;           // N_NODES*EMB f32
    ushort* Btbf = (ushort*)(xw + (size_t)N_NODES * EMB);    // NP*KP bf16
    float*  tailf = (float*)Btbf + (size_t)NP * KP / 2;      // CSR tail
    int*   cnt      = (int*)tailf;
    int*   cursor   = cnt + N_NODES;
    int*   offs     = cursor + N_NODES;
    int*   partials = offs + N_NODES;
    int*   esrc     = partials + 256;
    float* ecoef    = (float*)(esrc + N_EDGES);
    ushort* Watbf   = (ushort*)(ecoef + N_EDGES);            // KP*KP bf16 (1024x1024)
    ushort* rabf    = Watbf + (size_t)KP * KP;               // 128*KP bf16

    float* ws_f    = (float*)d_ws;
    float* logits  = ws_f;                 // 512
    int*   idxbuf  = (int*)(ws_f + 512);   // 64
    float* probsel = ws_f + 576;           // 64
    float* dinv_s  = ws_f + 640;           // 128
    float* ra      = ws_f + 768;           // 100000
    float* raw     = ws_f + 100768;        // 100000
    float* x1s     = ws_f + 200768;        // 100000
    float* dinv    = ws_f + 300768;        // 50500  -> total 351268 floats

    hipMemsetAsync(d_ws, 0, 351268 * sizeof(float), stream);
    hipMemsetAsync(cnt, 0, 2 * N_NODES * sizeof(int), stream);   // cnt + cursor

    // ---- small GCN pipeline (gemm via MFMA) ----
    logits_kernel<<<RELM1, 256, 0, stream>>>(num_feature, Wp, bp, logits);
    topk_kernel<<<1, 512, 0, stream>>>(logits, idxbuf, probsel);
    build_ra<<<2 * KTOP, 256, 0, stream>>>(anchor, num_feature, idxbuf, probsel, ra);
    transpose_bf16<<<dim3(16, 16), 256, 0, stream>>>(Wa, FEAT, FEAT, Watbf);
    convert_rabf<<<64, 256, 0, stream>>>(ra, rabf);
    gemm_mfma<<<dim3(1, 8), 256, 0, stream>>>(rabf, Watbf, raw, 2 * KTOP, FEAT, FEAT);
    deg_kernel<<<8, 256, 0, stream>>>(ra_edge, 2000, dinv_s);
    dinv_kernel<<<1, 256, 0, stream>>>(dinv_s, 2 * KTOP);
    scatter_small<<<500, 256, 0, stream>>>(ra_edge, raw, dinv_s, x1s);
    finalize_small<<<2 * KTOP, 256, 0, stream>>>(raw, dinv_s, ba, x1s);

    // ---- big graph CSR build ----
    hist_kernel<<<(N_EDGES + 255) / 256, 256, 0, stream>>>(edge_index, cnt);
    dinv_from_cnt<<<NB_SCAN, 256, 0, stream>>>(cnt, dinv);
    scan_blocks<<<NB_SCAN, 256, 0, stream>>>(cnt, offs, partials);
    scan_carry<<<1, 64, 0, stream>>>(partials);
    scan_add<<<NB_SCAN, 256, 0, stream>>>(offs, partials);
    fill_csr<<<(N_EDGES + 255) / 256, 256, 0, stream>>>(edge_index, offs, cursor, dinv,
                                                        esrc, ecoef);

    // ---- big GEMM (bf16 MFMA) ----
    convertA<<<4096, 256, 0, stream>>>(num_feature, Abf);
    transpose_bf16<<<dim3(16, 8), 256, 0, stream>>>(W1, FEAT, EMB, Btbf);
    gemm_mfma<<<dim3(MP / 128, NP / 128), 256, 0, stream>>>(Abf, Btbf, xw,
                                                            N_NODES, EMB, EMB);

    // ---- aggregation (pull) with fused bias+relu ----
    gather_big<<<(N_NODES + 3) / 4, 256, 0, stream>>>(esrc, ecoef, offs, cnt, xw, dinv,
                                                      b1, out_x);

    // ---- temp output ----
    copy_temp<<<4096, 256, 0, stream>>>(num_feature, out_temp);
    set_rows<<<KTOP, 256, 0, stream>>>(x1s, idxbuf, out_temp);

    // ---- scoring ----
    score_kernel<<<BATCH / 4, 256, 0, stream>>>(ent_emb, rel_emb, r_idx, e1_idx, e2_idx,
                                                conv_w, conv_b, fc_w, fc_b, out_score);
}